// Round 4
// baseline (250.670 us; speedup 1.0000x reference)
//
#include <hip/hip_runtime.h>
#include <math.h>

#define G_    64
#define NPG_  1600
#define N_    (G_*NPG_)     // 102400
#define EPG_  51200
#define E_    (G_*EPG_)     // 3276800
#define FIN_  512
#define HOUT_ 512
#define KEEP_ 1280

// ---------------------------------------------------------------------------
// K1: per-graph CSR build.  LDS degree hist -> shuffle scan -> LDS-cursor
// scatter INTO LDS (csrs), then coalesced uint4 copy-out.
// ---------------------------------------------------------------------------
__global__ __launch_bounds__(1024) void k_build(const int* __restrict__ esrc,
                                                const int* __restrict__ edst,
                                                int* __restrict__ offs,
                                                int* __restrict__ rend,
                                                float* __restrict__ dis,
                                                unsigned short* __restrict__ csr) {
  __shared__ __align__(16) unsigned short csrs[EPG_];   // 102,400 B
  __shared__ int hist[NPG_];                            // 6,400 B
  __shared__ int wsum[16];
  const int g = blockIdx.x, t = threadIdx.x;
  const int lane = t & 63, wid = t >> 6;
  const int eb = g * EPG_, nb = g * NPG_;

  for (int i = t; i < NPG_; i += 1024) hist[i] = 0;
  __syncthreads();
  for (int e = t; e < EPG_; e += 1024) atomicAdd(&hist[edst[eb + e] - nb], 1);
  __syncthreads();

  int c0 = 0, c1 = 0;
  if (t < 800) { c0 = hist[2 * t]; c1 = hist[2 * t + 1]; }
  const int val = c0 + c1;
  int incl = val;
#pragma unroll
  for (int m = 1; m < 64; m <<= 1) {
    const int u = __shfl_up(incl, m);
    if (lane >= m) incl += u;
  }
  if (lane == 63) wsum[wid] = incl;
  __syncthreads();
  int woff = 0;
  for (int w2 = 0; w2 < wid; ++w2) woff += wsum[w2];
  incl += woff;
  if (t < 800) {
    const int excl = incl - val;          // LOCAL edge offset
    const int p0 = excl, p1 = p0 + c0;
    offs[nb + 2 * t] = eb + p0;     rend[nb + 2 * t] = eb + p1;
    offs[nb + 2 * t + 1] = eb + p1; rend[nb + 2 * t + 1] = eb + p1 + c1;
    dis[nb + 2 * t] = rsqrtf((float)c0 + 1.0f);
    dis[nb + 2 * t + 1] = rsqrtf((float)c1 + 1.0f);
    hist[2 * t] = p0;          // reuse as LOCAL cursor
    hist[2 * t + 1] = p1;
  }
  __syncthreads();
  for (int e = t; e < EPG_; e += 1024) {
    const int s = esrc[eb + e];
    const int d = edst[eb + e] - nb;
    const int p = atomicAdd(&hist[d], 1);
    csrs[p] = (unsigned short)(s - nb);
  }
  __syncthreads();
  // coalesced copy-out: 6400 x uint4 (8 u16 each)
  const uint4* s4 = reinterpret_cast<const uint4*>(csrs);
  uint4* d4 = reinterpret_cast<uint4*>(csr + eb);
  for (int i = t; i < EPG_ / 8; i += 1024) d4[i] = s4[i];
}

// ---------------------------------------------------------------------------
// K2: hd[r] = (x[r] @ W1) * dis[r].
// W1 in LDS (32 KB, staged once).  TWO rows per thread: the 16 broadcast
// ds_read_b128 per k4 now feed 128 FMAs instead of 64 -- halves the LDS-pipe
// issue cost that bounded the previous version (per k4: 192 cyc LDS vs 128
// cyc VALU -> LDS-bound at ~120us).  New bounds: HBM 210MB ~ 33us > LDS
// ~20us > VALU ~14us.  Grid 200 x 256 thr (4 waves -> all 4 SIMDs/CU);
// thread t owns rows blk*512+t and +256 (per-lane row reads proven
// non-amplifying: FETCH was 105MB).
// ---------------------------------------------------------------------------
__global__ __launch_bounds__(256) void k_xw1(const float* __restrict__ x,
                                             const float* __restrict__ W1,
                                             const float* __restrict__ dis,
                                             float* __restrict__ hd) {
  __shared__ __align__(16) float wl[FIN_ * 16];   // 32,768 B
  const int t = threadIdx.x;
  {
    const float4* wg = reinterpret_cast<const float4*>(W1);
    float4* wd = reinterpret_cast<float4*>(wl);
    for (int i = t; i < FIN_ * 4; i += 256) wd[i] = wg[i];
  }
  __syncthreads();

  const int r0 = blockIdx.x * 512 + t;            // grid 200
  const int r1 = r0 + 256;
  const float4* xr0 = reinterpret_cast<const float4*>(x + (size_t)r0 * FIN_);
  const float4* xr1 = reinterpret_cast<const float4*>(x + (size_t)r1 * FIN_);
  float acc0[16], acc1[16];
#pragma unroll
  for (int j = 0; j < 16; ++j) { acc0[j] = 0.f; acc1[j] = 0.f; }

#pragma unroll 2
  for (int k4 = 0; k4 < 128; ++k4) {
    const float4 a = xr0[k4];
    const float4 b = xr1[k4];
    const float* w = wl + k4 * 64;                // LDS, same addr all lanes
#pragma unroll
    for (int j = 0; j < 16; ++j) {
      const float w0 = w[j];
      acc0[j] = fmaf(a.x, w0, acc0[j]);
      acc1[j] = fmaf(b.x, w0, acc1[j]);
    }
#pragma unroll
    for (int j = 0; j < 16; ++j) {
      const float w1 = w[16 + j];
      acc0[j] = fmaf(a.y, w1, acc0[j]);
      acc1[j] = fmaf(b.y, w1, acc1[j]);
    }
#pragma unroll
    for (int j = 0; j < 16; ++j) {
      const float w2 = w[32 + j];
      acc0[j] = fmaf(a.z, w2, acc0[j]);
      acc1[j] = fmaf(b.z, w2, acc1[j]);
    }
#pragma unroll
    for (int j = 0; j < 16; ++j) {
      const float w3 = w[48 + j];
      acc0[j] = fmaf(a.w, w3, acc0[j]);
      acc1[j] = fmaf(b.w, w3, acc1[j]);
    }
  }

  const float d0 = dis[r0], d1 = dis[r1];
  float4* p0 = reinterpret_cast<float4*>(hd) + (size_t)r0 * 4;
  float4* p1 = reinterpret_cast<float4*>(hd) + (size_t)r1 * 4;
  p0[0] = make_float4(acc0[0] * d0, acc0[1] * d0, acc0[2] * d0, acc0[3] * d0);
  p0[1] = make_float4(acc0[4] * d0, acc0[5] * d0, acc0[6] * d0, acc0[7] * d0);
  p0[2] = make_float4(acc0[8] * d0, acc0[9] * d0, acc0[10] * d0, acc0[11] * d0);
  p0[3] = make_float4(acc0[12] * d0, acc0[13] * d0, acc0[14] * d0, acc0[15] * d0);
  p1[0] = make_float4(acc1[0] * d1, acc1[1] * d1, acc1[2] * d1, acc1[3] * d1);
  p1[1] = make_float4(acc1[4] * d1, acc1[5] * d1, acc1[6] * d1, acc1[7] * d1);
  p1[2] = make_float4(acc1[8] * d1, acc1[9] * d1, acc1[10] * d1, acc1[11] * d1);
  p1[3] = make_float4(acc1[12] * d1, acc1[13] * d1, acc1[14] * d1, acc1[15] * d1);
}

// ---------------------------------------------------------------------------
// K3: conv1 gather, LDS-staged (per-graph hd slice = 102.4 KB in LDS).
// ---------------------------------------------------------------------------
__global__ __launch_bounds__(1024) void k_conv1l(
    const unsigned short* __restrict__ csr, const int* __restrict__ offs,
    const int* __restrict__ rend, const float* __restrict__ hd,
    const float* __restrict__ dis, const float* __restrict__ b1,
    const float* __restrict__ Wrel, const float* __restrict__ Wroot,
    float* __restrict__ h1, float* __restrict__ rarr, float* __restrict__ tarr) {
  __shared__ float hds[NPG_ * 16];                // 102,400 B
  const int g = blockIdx.x >> 2, q = blockIdx.x & 3;
  const int nb = g * NPG_;
  const int t = threadIdx.x;
  {
    const float4* src = reinterpret_cast<const float4*>(hd + (size_t)nb * 16);
    float4* dst = reinterpret_cast<float4*>(hds);
    for (int i = t; i < NPG_ * 4; i += 1024) dst[i] = src[i];
  }
  __syncthreads();
  const int c = t & 15;
  const float bb = b1[c], wr = Wrel[c], wo = Wroot[c];
  const int vend = q * 400 + 400;
  for (int vl = q * 400 + (t >> 4); vl < vend; vl += 64) {
    const int v = nb + vl;
    const int rs = offs[v], re = rend[v];
    float acc = 0.f;
    int k = rs;
    for (; k + 4 <= re; k += 4) {
      const int s0 = csr[k], s1 = csr[k + 1];
      const int s2 = csr[k + 2], s3 = csr[k + 3];
      acc += hds[s0 * 16 + c] + hds[s1 * 16 + c];
      acc += hds[s2 * 16 + c] + hds[s3 * 16 + c];
    }
    for (; k < re; ++k) acc += hds[csr[k] * 16 + c];
    const float dd = dis[v];
    float val = fmaf(acc + hds[vl * 16 + c], dd, bb);
    val = fmaxf(val, 0.f);
    h1[(size_t)v * 16 + c] = val;
    float r = val * wr;
    float tt = val * wo;
#pragma unroll
    for (int m = 1; m < 16; m <<= 1) {
      r += __shfl_xor(r, m);
      tt += __shfl_xor(tt, m);
    }
    if (c == 0) { rarr[v] = r; tarr[v] = tt; }
  }
}

// ---------------------------------------------------------------------------
// K4: per-graph fused score + radix-select top-K + filtered degree + h1w.
// Scans are shuffle-based.
// ---------------------------------------------------------------------------
__global__ __launch_bounds__(1024) void k_scoretopk(
    const unsigned short* __restrict__ csr, const int* __restrict__ offs,
    const int* __restrict__ rend, const float* __restrict__ rarr,
    const float* __restrict__ tarr, const float* __restrict__ brel,
    const float* __restrict__ h1, int* __restrict__ kept,
    float* __restrict__ dis2, float* __restrict__ h1w,
    float* __restrict__ out) {
  __shared__ float rar[NPG_];
  __shared__ float sar[NPG_];       // tarr, then score
  __shared__ int   ofs[NPG_];
  __shared__ int   ren[NPG_];
  __shared__ unsigned uu[NPG_];     // monotone keys
  __shared__ int   kp[NPG_];
  __shared__ float wv[NPG_];
  __shared__ int   hist[256];
  __shared__ int   part[16];        // per-wave scan sums
  __shared__ int   scal[2];         // lo, rem

  const int g = blockIdx.x, t = threadIdx.x;
  const int lane = t & 63, wid = t >> 6;
  const int nb = g * NPG_;

  // P0: stage
  for (int i = t; i < NPG_; i += 1024) {
    rar[i] = rarr[nb + i];
    sar[i] = tarr[nb + i];
    ofs[i] = offs[nb + i];
    ren[i] = rend[nb + i];
  }
  if (t == 0) { scal[0] = 0; scal[1] = KEEP_; }
  __syncthreads();

  // P1: score = tanh(sum rar[neighbors] + brel + tarr)
  const float br = brel[0];
  for (int v = t; v < NPG_; v += 1024) {
    const int rs = ofs[v], re = ren[v];
    float sum = 0.f;
    int k = rs;
    for (; k + 4 <= re; k += 4) {
      sum += rar[csr[k]] + rar[csr[k + 1]];
      sum += rar[csr[k + 2]] + rar[csr[k + 3]];
    }
    for (; k < re; ++k) sum += rar[csr[k]];
    const float s = tanhf(sum + br + sar[v]);
    sar[v] = s;
    const unsigned ub = __float_as_uint(s);
    uu[v] = (ub & 0x80000000u) ? ~ub : (ub | 0x80000000u);
  }
  __syncthreads();

  // P2: radix select (4 passes of 8 bits, MSB first)
  const unsigned maskTab[4] = {0u, 0xFF000000u, 0xFFFF0000u, 0xFFFFFF00u};
  const int shTab[4] = {24, 16, 8, 0};
  for (int pass = 0; pass < 4; ++pass) {
    const unsigned lo = (unsigned)scal[0];
    const int remc = scal[1];
    const unsigned msk = maskTab[pass];
    const int sh = shTab[pass];
    if (t < 256) hist[t] = 0;
    __syncthreads();
    for (int v = t; v < NPG_; v += 1024) {
      const unsigned u = uu[v];
      if (((u ^ lo) & msk) == 0) atomicAdd(&hist[(u >> sh) & 255], 1);
    }
    __syncthreads();
    int hv = 0;
    if (t < 256) hv = hist[t];
    int incl = hv;
#pragma unroll
    for (int m = 1; m < 64; m <<= 1) {
      const int u2 = __shfl_up(incl, m);
      if (lane >= m) incl += u2;
    }
    if (t < 256 && lane == 63) part[wid] = incl;  // waves 0..3
    __syncthreads();
    if (t < 256) {
      int woff = 0;
      for (int w2 = 0; w2 < wid; ++w2) woff += part[w2];
      const int tot = part[0] + part[1] + part[2] + part[3];
      const int sb = tot - (incl + woff) + hv;    // suffix sum from bin t
      const int sb1 = sb - hv;                    // suffix sum from bin t+1
      if (sb >= remc && sb1 < remc) {             // unique boundary bin
        scal[0] = (int)(lo | ((unsigned)t << sh));
        scal[1] = remc - sb1;
      }
    }
    __syncthreads();
  }
  const unsigned T = (unsigned)scal[0];
  const int remT = scal[1];

  // tie-break by index: keep first remT nodes with key == T (shuffle scan)
  const int i0 = 2 * t, i1 = 2 * t + 1;
  int f0 = 0, f1 = 0;
  if (i0 < NPG_) f0 = (uu[i0] == T);
  if (i1 < NPG_) f1 = (uu[i1] == T);
  int incl2 = f0 + f1;
#pragma unroll
  for (int m = 1; m < 64; m <<= 1) {
    const int u2 = __shfl_up(incl2, m);
    if (lane >= m) incl2 += u2;
  }
  if (lane == 63) part[wid] = incl2;
  __syncthreads();
  int woff2 = 0;
  for (int w2 = 0; w2 < wid; ++w2) woff2 += part[w2];
  const int excl = incl2 + woff2 - (f0 + f1);
  if (i0 < NPG_) kp[i0] = (uu[i0] > T) || (f0 && excl < remT);
  if (i1 < NPG_) kp[i1] = (uu[i1] > T) || (f1 && (excl + f0) < remT);
  __syncthreads();
  for (int v = t; v < NPG_; v += 1024) kept[nb + v] = kp[v];

  // P3: filtered degree -> dis2, wv = score * dis2 (0 for dropped)
  for (int v = t; v < NPG_; v += 1024) {
    float w = 0.f;
    if (kp[v]) {
      const int rs = ofs[v], re = ren[v];
      int c2 = 0, k = rs;
      for (; k + 4 <= re; k += 4) {
        c2 += kp[csr[k]] + kp[csr[k + 1]];
        c2 += kp[csr[k + 2]] + kp[csr[k + 3]];
      }
      for (; k < re; ++k) c2 += kp[csr[k]];
      const float d2 = rsqrtf((float)c2 + 1.0f);
      dis2[nb + v] = d2;
      w = sar[v] * d2;
    }
    wv[v] = w;
  }
  // zero the output slice for this graph
  if (t < HOUT_) out[g * HOUT_ + t] = 0.f;
  __syncthreads();

  // P4: h1w = h1 * wv[v]
  for (int i = t; i < NPG_ * 16; i += 1024)
    h1w[(size_t)nb * 16 + i] = h1[(size_t)nb * 16 + i] * wv[i >> 4];
}

// ---------------------------------------------------------------------------
// K5: conv2 gather, LDS-staged (same structure as K3).
// ---------------------------------------------------------------------------
__global__ __launch_bounds__(1024) void k_conv2l(
    const unsigned short* __restrict__ csr, const int* __restrict__ offs,
    const int* __restrict__ rend, const float* __restrict__ h1w,
    const int* __restrict__ kept, const float* __restrict__ dis2,
    float* __restrict__ y16) {
  __shared__ float hds[NPG_ * 16];                // 102,400 B
  const int g = blockIdx.x >> 2, q = blockIdx.x & 3;
  const int nb = g * NPG_;
  const int t = threadIdx.x;
  {
    const float4* src = reinterpret_cast<const float4*>(h1w + (size_t)nb * 16);
    float4* dst = reinterpret_cast<float4*>(hds);
    for (int i = t; i < NPG_ * 4; i += 1024) dst[i] = src[i];
  }
  __syncthreads();
  const int c = t & 15;
  const int vend = q * 400 + 400;
  for (int vl = q * 400 + (t >> 4); vl < vend; vl += 64) {
    const int v = nb + vl;
    if (!kept[v]) continue;                       // uniform per 16-group
    const int rs = offs[v], re = rend[v];
    float acc = 0.f;
    int k = rs;
    for (; k + 4 <= re; k += 4) {
      const int s0 = csr[k], s1 = csr[k + 1];
      const int s2 = csr[k + 2], s3 = csr[k + 3];
      acc += hds[s0 * 16 + c] + hds[s1 * 16 + c];
      acc += hds[s2 * 16 + c] + hds[s3 * 16 + c];
    }
    for (; k < re; ++k) acc += hds[csr[k] * 16 + c];
    acc += hds[vl * 16 + c];                      // self loop
    y16[(size_t)v * 16 + c] = acc * dis2[v];
  }
}

// ---------------------------------------------------------------------------
// K6: out[g] += relu(y16[v]@W2 + b2)/K  fused GEMM+ReLU+mean-pool.
// ---------------------------------------------------------------------------
__global__ __launch_bounds__(256, 1) void k_gemm2pool(const float* __restrict__ y16,
                                                      const int* __restrict__ kept,
                                                      const float* __restrict__ W2,
                                                      const float* __restrict__ b2,
                                                      float* __restrict__ out) {
  __shared__ float red[256];
  const int blk = blockIdx.x;                     // grid 2048
  const int g = blk >> 5;
  const int sub = blk & 31;
  const int jbase = (sub & 1) * 256;
  const int nstart = g * NPG_ + (sub >> 1) * 100;
  const int tid = threadIdx.x;
  const int wave = tid >> 6, lane = tid & 63;

  float w[16][4];
#pragma unroll
  for (int k = 0; k < 16; ++k)
#pragma unroll
    for (int c = 0; c < 4; ++c)
      w[k][c] = W2[k * HOUT_ + jbase + lane + c * 64];
  float b2r[4];
#pragma unroll
  for (int c = 0; c < 4; ++c) b2r[c] = b2[jbase + lane + c * 64];

  float acc[4] = {0.f, 0.f, 0.f, 0.f};
  for (int i = wave; i < 100; i += 4) {
    const int v = nstart + i;
    if (!kept[v]) continue;                       // wave-uniform
    const float4* yp = reinterpret_cast<const float4*>(y16 + (size_t)v * 16);
    float4 q0 = yp[0], q1 = yp[1], q2 = yp[2], q3 = yp[3];
    const float yv[16] = {q0.x, q0.y, q0.z, q0.w, q1.x, q1.y, q1.z, q1.w,
                          q2.x, q2.y, q2.z, q2.w, q3.x, q3.y, q3.z, q3.w};
    float z[4] = {b2r[0], b2r[1], b2r[2], b2r[3]};
#pragma unroll
    for (int k = 0; k < 16; ++k)
#pragma unroll
      for (int c = 0; c < 4; ++c)
        z[c] = fmaf(yv[k], w[k][c], z[c]);
#pragma unroll
    for (int c = 0; c < 4; ++c) acc[c] += fmaxf(z[c], 0.f);
  }

  red[tid] = 0.f;
  __syncthreads();
#pragma unroll
  for (int c = 0; c < 4; ++c) atomicAdd(&red[lane + 64 * c], acc[c]);
  __syncthreads();
  atomicAdd(&out[g * HOUT_ + jbase + tid], red[tid] * (1.0f / (float)KEEP_));
}

// ---------------------------------------------------------------------------
extern "C" void kernel_launch(void* const* d_in, const int* in_sizes, int n_in,
                              void* d_out, int out_size, void* d_ws, size_t ws_size,
                              hipStream_t stream) {
  (void)in_sizes; (void)n_in; (void)out_size; (void)ws_size;
  const float* x     = (const float*)d_in[0];
  const int*   ei    = (const int*)  d_in[1];
  const float* W1    = (const float*)d_in[3];
  const float* b1    = (const float*)d_in[4];
  const float* Wrel  = (const float*)d_in[5];
  const float* brel  = (const float*)d_in[6];
  const float* Wroot = (const float*)d_in[7];
  const float* W2    = (const float*)d_in[8];
  const float* b2    = (const float*)d_in[9];
  const int* esrc = ei;
  const int* edst = ei + E_;

  // slab quarters: hd / h1 / h1w / y16
  char* ws = (char*)d_ws;
  float*          hd    = (float*)(ws);                    // q0: 6,553,600 B
  float*          h1    = (float*)(ws + 6553600);          // q1
  float*          h1w   = (float*)(ws + 13107200);         // q2
  float*          y16   = (float*)(ws + 19660800);         // q3
  unsigned short* csr   = (unsigned short*)(ws + 26214400);// 6,553,600 B
  int*            offs  = (int*)(ws + 32768000);
  int*            rendp = (int*)(ws + 33177600);
  float*          dis   = (float*)(ws + 33587200);
  int*            kept  = (int*)(ws + 33996800);
  float*          rarr  = (float*)(ws + 34406400);
  float*          tarr  = (float*)(ws + 34816000);
  float*          dis2  = (float*)(ws + 35225600);
  float*          out   = (float*)d_out;

  hipLaunchKernelGGL(k_build,     dim3(G_),    dim3(1024), 0, stream,
                     esrc, edst, offs, rendp, dis, csr);
  hipLaunchKernelGGL(k_xw1,       dim3(200),   dim3(256),  0, stream,
                     x, W1, dis, hd);
  hipLaunchKernelGGL(k_conv1l,    dim3(256),   dim3(1024), 0, stream,
                     csr, offs, rendp, hd, dis, b1, Wrel, Wroot, h1, rarr, tarr);
  hipLaunchKernelGGL(k_scoretopk, dim3(G_),    dim3(1024), 0, stream,
                     csr, offs, rendp, rarr, tarr, brel, h1, kept, dis2, h1w, out);
  hipLaunchKernelGGL(k_conv2l,    dim3(256),   dim3(1024), 0, stream,
                     csr, offs, rendp, h1w, kept, dis2, y16);
  hipLaunchKernelGGL(k_gemm2pool, dim3(2048),  dim3(256),  0, stream,
                     y16, kept, W2, b2, out);
}